// Round 4
// baseline (310.011 us; speedup 1.0000x reference)
//
#include <hip/hip_runtime.h>
#include <hip/hip_bf16.h>
#include <math.h>

// Problem constants: B=4,H=8,S=4096,D=128,BT=64
#define Gp  32      // B*H
#define Sp  4096
#define Dp  128
#define BTp 64
#define NCp 64      // S/BT

typedef __attribute__((ext_vector_type(8))) short bf16x8;
typedef __attribute__((ext_vector_type(4))) float f32x4;

#define MFMA(a,b,c) __builtin_amdgcn_mfma_f32_16x16x32_bf16((a),(b),(c),0,0,0)

// XOR swizzle for [128][64] bf16 transposed tiles: elem (d,i) at
//   d*64 + (((i>>3) ^ (((d&15)>>1))) << 3) + (i&7)
#define TSWZ(d, slot) ((((slot) ^ (((d) & 15) >> 1)) << 3))

__device__ inline unsigned pack2(float lo, float hi) {
    __hip_bfloat162 h = __float22bfloat162_rn(make_float2(lo, hi));  // v_cvt_pk_bf16_f32
    union { __hip_bfloat162 v; unsigned u; } t; t.v = h; return t.u;
}
__device__ inline float bflo(unsigned u) { union { unsigned u; float f; } t; t.u = u << 16; return t.f; }
__device__ inline float bfhi(unsigned u) { union { unsigned u; float f; } t; t.u = u & 0xffff0000u; return t.f; }

// ---------------------------------------------------------------------------
// Kernel 0: per-chunk beta statistics (cum log-beta, exp decays, totals).
// ---------------------------------------------------------------------------
__global__ __launch_bounds__(256) void gdn_beta(
    const float* __restrict__ beta, float* __restrict__ cum_buf,
    float* __restrict__ dte_buf, float* __restrict__ dfs_buf,
    float* __restrict__ tot_buf)
{
    const int tid = threadIdx.x, lane = tid & 63, w = tid >> 6;
    const int cc = blockIdx.x * 4 + w;             // global chunk id
    const int g = cc >> 6, c = cc & 63;
    const size_t bbase = (size_t)g * Sp + (size_t)c * BTp;
    float x = logf(beta[bbase + lane] + 1e-6f);
    #pragma unroll
    for (int off = 1; off < 64; off <<= 1) {
        float n = __shfl_up(x, off, 64);
        if (lane >= off) x += n;
    }
    const float tot = __shfl(x, 63, 64);
    cum_buf[bbase + lane] = x;
    dfs_buf[bbase + lane] = expf(x);
    dte_buf[bbase + lane] = expf(tot - x);
    if (lane == 63) tot_buf[g * NCp + c] = tot;
}

// ---------------------------------------------------------------------------
// Staging: one k/v register set -> s_k (row-major swizzled), s_vt, s_kt.
// Thread owns 8 rows (rg) x 4 cols (dd).
// ---------------------------------------------------------------------------
__device__ __forceinline__ void stage_chunk(
    unsigned short* __restrict__ s_k, unsigned short* __restrict__ s_vt,
    unsigned short* __restrict__ s_kt,
    int dd, int rg, const float4* kx, const float4* vx,
    const float4 dt0, const float4 dt1)
{
    const int i0 = 8 * rg;
    #pragma unroll
    for (int r = 0; r < 8; ++r) {
        const int i = i0 + r;
        const int ad = i * 128 + (((dd >> 3) ^ (i & 15)) << 3) + (dd & 7);
        uint2 pw; pw.x = pack2(kx[r].x, kx[r].y); pw.y = pack2(kx[r].z, kx[r].w);
        *(uint2*)&s_k[ad] = pw;
    }
    {
        uint4 t;
        t.x = pack2(vx[0].x, vx[1].x); t.y = pack2(vx[2].x, vx[3].x);
        t.z = pack2(vx[4].x, vx[5].x); t.w = pack2(vx[6].x, vx[7].x);
        *(uint4*)&s_vt[(dd + 0) * 64 + TSWZ(dd + 0, rg)] = t;
        t.x = pack2(vx[0].y, vx[1].y); t.y = pack2(vx[2].y, vx[3].y);
        t.z = pack2(vx[4].y, vx[5].y); t.w = pack2(vx[6].y, vx[7].y);
        *(uint4*)&s_vt[(dd + 1) * 64 + TSWZ(dd + 1, rg)] = t;
        t.x = pack2(vx[0].z, vx[1].z); t.y = pack2(vx[2].z, vx[3].z);
        t.z = pack2(vx[4].z, vx[5].z); t.w = pack2(vx[6].z, vx[7].z);
        *(uint4*)&s_vt[(dd + 2) * 64 + TSWZ(dd + 2, rg)] = t;
        t.x = pack2(vx[0].w, vx[1].w); t.y = pack2(vx[2].w, vx[3].w);
        t.z = pack2(vx[4].w, vx[5].w); t.w = pack2(vx[6].w, vx[7].w);
        *(uint4*)&s_vt[(dd + 3) * 64 + TSWZ(dd + 3, rg)] = t;
    }
    {
        const float d0 = dt0.x, d1 = dt0.y, d2 = dt0.z, d3 = dt0.w;
        const float d4 = dt1.x, d5 = dt1.y, d6 = dt1.z, d7 = dt1.w;
        uint4 t;
        t.x = pack2(kx[0].x * d0, kx[1].x * d1); t.y = pack2(kx[2].x * d2, kx[3].x * d3);
        t.z = pack2(kx[4].x * d4, kx[5].x * d5); t.w = pack2(kx[6].x * d6, kx[7].x * d7);
        *(uint4*)&s_kt[(dd + 0) * 64 + TSWZ(dd + 0, rg)] = t;
        t.x = pack2(kx[0].y * d0, kx[1].y * d1); t.y = pack2(kx[2].y * d2, kx[3].y * d3);
        t.z = pack2(kx[4].y * d4, kx[5].y * d5); t.w = pack2(kx[6].y * d6, kx[7].y * d7);
        *(uint4*)&s_kt[(dd + 1) * 64 + TSWZ(dd + 1, rg)] = t;
        t.x = pack2(kx[0].z * d0, kx[1].z * d1); t.y = pack2(kx[2].z * d2, kx[3].z * d3);
        t.z = pack2(kx[4].z * d4, kx[5].z * d5); t.w = pack2(kx[6].z * d6, kx[7].z * d7);
        *(uint4*)&s_kt[(dd + 2) * 64 + TSWZ(dd + 2, rg)] = t;
        t.x = pack2(kx[0].w * d0, kx[1].w * d1); t.y = pack2(kx[2].w * d2, kx[3].w * d3);
        t.z = pack2(kx[4].w * d4, kx[5].w * d5); t.w = pack2(kx[6].w * d6, kx[7].w * d7);
        *(uint4*)&s_kt[(dd + 3) * 64 + TSWZ(dd + 3, rg)] = t;
    }
}

__device__ __forceinline__ void pack_q(const float4* qa, const float4* qb, bf16x8* qf)
{
    #pragma unroll
    for (int ks = 0; ks < 4; ++ks) {
        union { bf16x8 v; unsigned ui[4]; } t;
        t.ui[0] = pack2(qa[ks].x, qa[ks].y); t.ui[1] = pack2(qa[ks].z, qa[ks].w);
        t.ui[2] = pack2(qb[ks].x, qb[ks].y); t.ui[3] = pack2(qb[ks].z, qb[ks].w);
        qf[ks] = t.v;
    }
}

// ---------------------------------------------------------------------------
// Per-chunk compute (after LDS staged): GEMM1 swapped + epilogue, in-register
// P transpose, GEMM3 (updT), GEMM2 (out_intra), qs = bf16(q)*dfs store.
// ---------------------------------------------------------------------------
__device__ __forceinline__ void intra_compute(
    const float x, const bf16x8* qf,
    const unsigned short* s_k, const unsigned short* s_vt,
    const unsigned short* s_kt,
    const int w, const int m16, const int quad,
    const size_t base, const size_t cid,
    float* __restrict__ out, unsigned short* __restrict__ outi,
    unsigned short* __restrict__ upd, unsigned short* __restrict__ qs)
{
    // ---- GEMM1 swapped: accP[nt] = C[j][i], j = 16nt+4quad+r, i = 16w+m16 ----
    f32x4 accP[4] = {};
    #pragma unroll
    for (int nt = 0; nt < 4; ++nt) {
        if (nt <= w) {
            #pragma unroll
            for (int ks = 0; ks < 4; ++ks) {
                const bf16x8 kf = *(const bf16x8*)&s_k[(16 * nt + m16) * 128 + (((quad + 4 * ks) ^ m16) << 3)];
                accP[nt] = MFMA(kf, qf[ks], accP[nt]);
            }
        }
    }

    // ---- epilogue: mask + decay in registers, pack to bf16 pairs ----
    const float ci = __shfl(x, 16 * w + m16, 64);
    unsigned p_pk[4][2];
    #pragma unroll
    for (int nt = 0; nt < 4; ++nt) { p_pk[nt][0] = 0u; p_pk[nt][1] = 0u; }
    #pragma unroll
    for (int nt = 0; nt < 4; ++nt) {
        if (nt <= w) {
            float pm[4];
            #pragma unroll
            for (int r = 0; r < 4; ++r) {
                const int j = 16 * nt + 4 * quad + r;
                const float cj = __shfl(x, j, 64);
                float val = accP[nt][r] * expf(ci - cj);
                if (nt == w) val = (16 * w + m16 >= j) ? val : 0.f;
                pm[r] = val;
            }
            p_pk[nt][0] = pack2(pm[0], pm[1]);
            p_pk[nt][1] = pack2(pm[2], pm[3]);
        }
    }

    // ---- qs = qf * dfs[i] (bf16), feeds gdn_inter's B-frags directly ----
    if (qs) {
        const float sc = expf(ci);
        #pragma unroll
        for (int ks = 0; ks < 4; ++ks) {
            union { bf16x8 v; unsigned ui[4]; } t; t.v = qf[ks];
            uint4 o;
            o.x = pack2(bflo(t.ui[0]) * sc, bfhi(t.ui[0]) * sc);
            o.y = pack2(bflo(t.ui[1]) * sc, bfhi(t.ui[1]) * sc);
            o.z = pack2(bflo(t.ui[2]) * sc, bfhi(t.ui[2]) * sc);
            o.w = pack2(bflo(t.ui[3]) * sc, bfhi(t.ui[3]) * sc);
            *(uint4*)&qs[base + (size_t)(16 * w + m16) * Dp + quad * 8 + ks * 32] = o;
        }
    }

    // ---- in-register transpose: build GEMM2 B-frags af[ks] = P rows i over K=j ----
    bf16x8 af[2];
    #pragma unroll
    for (int ks = 0; ks < 2; ++ks) {
        if (ks <= (w >> 1)) {
            union { bf16x8 v; unsigned ui[4]; } t;
            #pragma unroll
            for (int m = 0; m < 4; ++m) {
                const int src = m16 + 16 * (2 * (quad & 1) + (m >> 1));
                const unsigned aA = (unsigned)__shfl((int)p_pk[2 * ks][m & 1], src, 64);
                const unsigned aB = (unsigned)__shfl((int)p_pk[2 * ks + 1][m & 1], src, 64);
                t.ui[m] = (quad >> 1) ? aB : aA;
            }
            af[ks] = t.v;
        }
    }

    // ---- GEMM3 swapped: C[d][e] = sum_i (k*dte)[i][d] * v[i][e] ----
    {
        f32x4 accU[2][8] = {};
        #pragma unroll
        for (int ks = 0; ks < 2; ++ks) {
            const int sw = TSWZ(m16, quad + 4 * ks);
            const bf16x8 b0 = *(const bf16x8*)&s_vt[(16 * (2 * w)     + m16) * 64 + sw];
            const bf16x8 b1 = *(const bf16x8*)&s_vt[(16 * (2 * w + 1) + m16) * 64 + sw];
            #pragma unroll
            for (int nt = 0; nt < 8; ++nt) {
                const bf16x8 a = *(const bf16x8*)&s_kt[(16 * nt + m16) * 64 + sw];
                accU[0][nt] = MFMA(a, b0, accU[0][nt]);
                accU[1][nt] = MFMA(a, b1, accU[1][nt]);
            }
        }
        unsigned short* ub = upd + cid * (size_t)(Dp * Dp);
        #pragma unroll
        for (int mt = 0; mt < 2; ++mt) {
            const int e = 16 * (2 * w + mt) + m16;
            #pragma unroll
            for (int nt = 0; nt < 8; ++nt) {
                uint2 pw;
                pw.x = pack2(accU[mt][nt][0], accU[mt][nt][1]);
                pw.y = pack2(accU[mt][nt][2], accU[mt][nt][3]);
                *(uint2*)&ub[(size_t)e * Dp + 16 * nt + 4 * quad] = pw;
            }
        }
    }

    // ---- GEMM2 swapped: out_intra[i][d]; C[d][i] = sum_j v[j][d] * P[i][j] ----
    {
        f32x4 accO[8] = {};
        #pragma unroll
        for (int ks = 0; ks < 2; ++ks) {
            if (ks <= (w >> 1)) {
                const int sw = TSWZ(m16, quad + 4 * ks);
                #pragma unroll
                for (int nt = 0; nt < 8; ++nt) {
                    const bf16x8 a = *(const bf16x8*)&s_vt[(16 * nt + m16) * 64 + sw];
                    accO[nt] = MFMA(a, af[ks], accO[nt]);
                }
            }
        }
        const int i = 16 * w + m16;
        if (outi) {
            #pragma unroll
            for (int nt = 0; nt < 8; ++nt) {
                uint2 pw;
                pw.x = pack2(accO[nt][0], accO[nt][1]);
                pw.y = pack2(accO[nt][2], accO[nt][3]);
                *(uint2*)&outi[base + (size_t)i * Dp + 16 * nt + 4 * quad] = pw;
            }
        } else {
            #pragma unroll
            for (int nt = 0; nt < 8; ++nt) {
                float4 st;
                st.x = accO[nt][0]; st.y = accO[nt][1];
                st.z = accO[nt][2]; st.w = accO[nt][3];
                *(float4*)&out[base + (size_t)i * Dp + 16 * nt + 4 * quad] = st;
            }
        }
    }
}

// ---------------------------------------------------------------------------
// Kernel A: TWO chunks per block, software-pipelined: chunk c1's k/v loads
// are issued before the barrier and stay in flight across chunk c0's entire
// compute phase.  1024 blocks x 256 threads, LDS 48 KB.
// ---------------------------------------------------------------------------
__global__ __launch_bounds__(256, 2) void gdn_intra(
    const float* __restrict__ q, const float* __restrict__ k,
    const float* __restrict__ v, const float* __restrict__ cum_buf,
    const float* __restrict__ dte_buf,
    float* __restrict__ out, unsigned short* __restrict__ outi,
    unsigned short* __restrict__ upd, unsigned short* __restrict__ qs)
{
    __shared__ unsigned short s_k [64 * 128];
    __shared__ unsigned short s_vt[128 * 64];
    __shared__ unsigned short s_kt[128 * 64];

    const int blk = blockIdx.x, g = blk >> 5, pr = blk & 31;
    const int c0 = 2 * pr;
    const int tid = threadIdx.x, lane = tid & 63, w = tid >> 6;
    const int m16 = lane & 15, quad = lane >> 4;
    const int dd = 4 * (tid & 31), rg = tid >> 5, i0 = 8 * rg;

    const size_t cid0  = (size_t)g * NCp + c0, cid1 = cid0 + 1;
    const size_t bb0   = (size_t)g * Sp + (size_t)c0 * BTp, bb1 = bb0 + BTp;
    const size_t base0 = bb0 * Dp, base1 = bb1 * Dp;

    // ---- chunk 0 loads (all issued back-to-back) ----
    const float x0 = cum_buf[bb0 + lane];
    float4 kx[8], vx[8];
    {
        const float* kp = k + base0 + (size_t)i0 * Dp + dd;
        const float* vp = v + base0 + (size_t)i0 * Dp + dd;
        #pragma unroll
        for (int r = 0; r < 8; ++r) kx[r] = *(const float4*)(kp + (size_t)r * Dp);
        #pragma unroll
        for (int r = 0; r < 8; ++r) vx[r] = *(const float4*)(vp + (size_t)r * Dp);
    }
    const float4 dt00 = *(const float4*)(dte_buf + bb0 + i0);
    const float4 dt01 = *(const float4*)(dte_buf + bb0 + i0 + 4);
    float4 qa[4], qb[4];
    {
        const float* qrow = q + base0 + (size_t)(16 * w + m16) * Dp + quad * 8;
        #pragma unroll
        for (int ks = 0; ks < 4; ++ks) {
            qa[ks] = *(const float4*)(qrow + ks * 32);
            qb[ks] = *(const float4*)(qrow + ks * 32 + 4);
        }
    }

    // ---- stage chunk 0 into LDS; pack q0 ----
    stage_chunk(s_k, s_vt, s_kt, dd, rg, kx, vx, dt00, dt01);
    bf16x8 qf0[4];
    pack_q(qa, qb, qf0);

    // ---- PREFETCH chunk 1 (k/v/dte/cum) before the barrier ----
    const float x1 = cum_buf[bb1 + lane];
    float4 kx1[8], vx1[8];
    {
        const float* kp = k + base1 + (size_t)i0 * Dp + dd;
        const float* vp = v + base1 + (size_t)i0 * Dp + dd;
        #pragma unroll
        for (int r = 0; r < 8; ++r) kx1[r] = *(const float4*)(kp + (size_t)r * Dp);
        #pragma unroll
        for (int r = 0; r < 8; ++r) vx1[r] = *(const float4*)(vp + (size_t)r * Dp);
    }
    const float4 dt10 = *(const float4*)(dte_buf + bb1 + i0);
    const float4 dt11 = *(const float4*)(dte_buf + bb1 + i0 + 4);

    __syncthreads();

    // ---- q1 prefetch (in flight across chunk-0 compute) ----
    float4 qa1[4], qb1[4];
    {
        const float* qrow = q + base1 + (size_t)(16 * w + m16) * Dp + quad * 8;
        #pragma unroll
        for (int ks = 0; ks < 4; ++ks) {
            qa1[ks] = *(const float4*)(qrow + ks * 32);
            qb1[ks] = *(const float4*)(qrow + ks * 32 + 4);
        }
    }

    // ---- compute chunk 0 (c1 loads in flight underneath) ----
    intra_compute(x0, qf0, s_k, s_vt, s_kt, w, m16, quad,
                  base0, cid0, out, outi, upd, qs);

    __syncthreads();   // all waves done reading chunk-0 LDS

    // ---- stage chunk 1 from prefetched registers ----
    stage_chunk(s_k, s_vt, s_kt, dd, rg, kx1, vx1, dt10, dt11);
    bf16x8 qf1[4];
    pack_q(qa1, qb1, qf1);

    __syncthreads();

    // ---- compute chunk 1 ----
    intra_compute(x1, qf1, s_k, s_vt, s_kt, w, m16, quad,
                  base1, cid1, out, outi, upd, qs);
}

// ---------------------------------------------------------------------------
// Kernel B: sequential inter-chunk scan over bf16 states, fp32 accumulation.
// ---------------------------------------------------------------------------
__global__ __launch_bounds__(128) void gdn_scan(
    unsigned short* __restrict__ upd, const float* __restrict__ tot_buf)
{
    const int g = blockIdx.x >> 4, slab = blockIdx.x & 15, tid = threadIdx.x;
    __shared__ float s_e[NCp];
    if (tid < NCp) s_e[tid] = expf(tot_buf[g * NCp + tid]);
    __syncthreads();
    uint4* b = (uint4*)(upd + (size_t)g * NCp * Dp * Dp) + slab * 128 + tid;
    float s0 = 0.f, s1 = 0.f, s2 = 0.f, s3 = 0.f;
    float s4 = 0.f, s5 = 0.f, s6 = 0.f, s7 = 0.f;
    uint4 pf[4];
    #pragma unroll
    for (int j = 0; j < 4; ++j) pf[j] = b[(size_t)j * 2048];
    #pragma unroll
    for (int cc = 0; cc < NCp; ++cc) {
        const uint4 cur = pf[cc & 3];
        if (cc + 4 < NCp) pf[cc & 3] = b[(size_t)(cc + 4) * 2048];
        const float e = s_e[cc];
        uint4 stq;
        stq.x = pack2(s0, s1); stq.y = pack2(s2, s3);
        stq.z = pack2(s4, s5); stq.w = pack2(s6, s7);
        b[(size_t)cc * 2048] = stq;
        s0 = s0 * e + bflo(cur.x); s1 = s1 * e + bfhi(cur.x);
        s2 = s2 * e + bflo(cur.y); s3 = s3 * e + bfhi(cur.y);
        s4 = s4 * e + bflo(cur.z); s5 = s5 * e + bfhi(cur.z);
        s6 = s6 * e + bflo(cur.w); s7 = s7 * e + bfhi(cur.w);
    }
}

// ---------------------------------------------------------------------------
// Kernel C: out[i][e] = out_intra[i][e] + qs[i][:] @ S_c[:][e].  Pure stream:
// when qs is available there is NO VALU between loads — q fragments load
// directly as bf16, outi as bf16, state as bf16; 44 independent loads.
// ---------------------------------------------------------------------------
__global__ __launch_bounds__(256) void gdn_inter(
    const float* __restrict__ q, const unsigned short* __restrict__ state,
    const float* __restrict__ dfs_buf, const unsigned short* __restrict__ outi,
    const unsigned short* __restrict__ qs, float* __restrict__ out)
{
    const int blk = blockIdx.x, g = blk >> 6, c = blk & 63;
    const int tid = threadIdx.x, lane = tid & 63, w = tid >> 6;
    const int m16 = lane & 15, quad = lane >> 4;
    const size_t base  = ((size_t)g * Sp + (size_t)c * BTp) * Dp;
    const size_t bbase = (size_t)g * Sp + (size_t)c * BTp;
    const unsigned short* sb = state + (size_t)blk * Dp * Dp;
    const int i = 16 * w + m16;                    // this lane's output row

    bf16x8 qf[4];
    if (qs) {
        const unsigned short* qrow = qs + base + (size_t)i * Dp + quad * 8;
        #pragma unroll
        for (int ks = 0; ks < 4; ++ks)
            qf[ks] = *(const bf16x8*)(qrow + ks * 32);
    } else {
        const float scale = dfs_buf[bbase + i];
        const float* qrow = q + base + (size_t)i * Dp + quad * 8;
        #pragma unroll
        for (int ks = 0; ks < 4; ++ks) {
            const float4 a = *(const float4*)(qrow + ks * 32);
            const float4 b = *(const float4*)(qrow + ks * 32 + 4);
            union { bf16x8 v; unsigned ui[4]; } t;
            t.ui[0] = pack2(a.x * scale, a.y * scale);
            t.ui[1] = pack2(a.z * scale, a.w * scale);
            t.ui[2] = pack2(b.x * scale, b.y * scale);
            t.ui[3] = pack2(b.z * scale, b.w * scale);
            qf[ks] = t.v;
        }
    }

    // preload the += operand while MFMAs run
    float ovf[8][4];
    if (outi) {
        #pragma unroll
        for (int nt = 0; nt < 8; ++nt) {
            const uint2 pw = *(const uint2*)&outi[base + (size_t)i * Dp + 16 * nt + 4 * quad];
            ovf[nt][0] = bflo(pw.x); ovf[nt][1] = bfhi(pw.x);
            ovf[nt][2] = bflo(pw.y); ovf[nt][3] = bfhi(pw.y);
        }
    } else {
        #pragma unroll
        for (int nt = 0; nt < 8; ++nt) {
            const float4 o = *(const float4*)&out[base + (size_t)i * Dp + 16 * nt + 4 * quad];
            ovf[nt][0] = o.x; ovf[nt][1] = o.y; ovf[nt][2] = o.z; ovf[nt][3] = o.w;
        }
    }

    f32x4 acc[8] = {};
    #pragma unroll
    for (int ks = 0; ks < 4; ++ks) {
        bf16x8 afr[8];
        #pragma unroll
        for (int nt = 0; nt < 8; ++nt)
            afr[nt] = *(const bf16x8*)(sb + (16 * nt + m16) * Dp + quad * 8 + ks * 32);
        #pragma unroll
        for (int nt = 0; nt < 8; ++nt)
            acc[nt] = MFMA(afr[nt], qf[ks], acc[nt]);   // C[e][i]
    }
    #pragma unroll
    for (int nt = 0; nt < 8; ++nt) {
        float4 st;
        st.x = ovf[nt][0] + acc[nt][0]; st.y = ovf[nt][1] + acc[nt][1];
        st.z = ovf[nt][2] + acc[nt][2]; st.w = ovf[nt][3] + acc[nt][3];
        *(float4*)&out[base + (size_t)i * Dp + 16 * nt + 4 * quad] = st;
    }
}

// ---------------------------------------------------------------------------
extern "C" void kernel_launch(void* const* d_in, const int* in_sizes, int n_in,
                              void* d_out, int out_size, void* d_ws, size_t ws_size,
                              hipStream_t stream) {
    const float* q    = (const float*)d_in[0];
    const float* k    = (const float*)d_in[1];
    const float* v    = (const float*)d_in[2];
    const float* beta = (const float*)d_in[3];
    float* out = (float*)d_out;

    unsigned short* upd = (unsigned short*)d_ws;             // G*NC*D*D bf16 (updT/stateT)
    float* tot_buf = (float*)(upd + (size_t)Gp * NCp * Dp * Dp);
    float* dfs_buf = tot_buf + Gp * NCp;
    float* cum_buf = dfs_buf + (size_t)Gp * Sp;
    float* dte_buf = cum_buf + (size_t)Gp * Sp;
    unsigned short* outi = (unsigned short*)(dte_buf + (size_t)Gp * Sp);
    unsigned short* qs   = outi + (size_t)Gp * Sp * Dp;
    const size_t need_oi = (size_t)((char*)(outi + (size_t)Gp * Sp * Dp) - (char*)d_ws);
    const size_t need_qs = (size_t)((char*)(qs   + (size_t)Gp * Sp * Dp) - (char*)d_ws);
    if (ws_size < need_oi) outi = nullptr;   // fallback: f32 RMW through out
    if (ws_size < need_qs) qs   = nullptr;   // fallback: f32 q + dfs scale

    gdn_beta <<<Gp * NCp / 4, 256, 0, stream>>>(beta, cum_buf, dte_buf, dfs_buf, tot_buf);
    gdn_intra<<<Gp * NCp / 2, 256, 0, stream>>>(q, k, v, cum_buf, dte_buf, out, outi, upd, qs);
    gdn_scan <<<Gp * 16, 128, 0, stream>>>(upd, tot_buf);
    gdn_inter<<<Gp * NCp, 256, 0, stream>>>(q, upd, dfs_buf, outi, qs, out);
}